// Round 14
// baseline (859.726 us; speedup 1.0000x reference)
//
#include <hip/hip_runtime.h>

typedef __attribute__((ext_vector_type(8))) short short8;
typedef __attribute__((ext_vector_type(4))) float f32x4;
typedef __attribute__((ext_vector_type(2))) unsigned uint2v;

__device__ __forceinline__ ushort f2bf(float x) {
  unsigned u = __builtin_bit_cast(unsigned, x);
  u = (u + 0x7fffu + ((u >> 16) & 1u)) >> 16;
  return (ushort)u;
}
__device__ __forceinline__ float bf2f(ushort x) {
  return __builtin_bit_cast(float, ((unsigned)x) << 16);
}

// global -> LDS direct DMA (k_gemm staging)
#define AS1CP(p) ((const __attribute__((address_space(1))) unsigned int*)(p))
#define AS3CP(p) ((__attribute__((address_space(3))) unsigned int*)(p))
#define GLDS(g, l, SZ) __builtin_amdgcn_global_load_lds(AS1CP(g), AS3CP(l), SZ, 0, 0)

// ---------------- input fp32 -> bf16 ----------------
__global__ __launch_bounds__(256) void k_cvt(const float* __restrict__ in,
                                             ushort* __restrict__ out, int n4) {
  int i = blockIdx.x * 256 + threadIdx.x;
  if (i >= n4) return;
  float4 v = reinterpret_cast<const float4*>(in)[i];
  ushort4 o;
  o.x = f2bf(v.x); o.y = f2bf(v.y); o.z = f2bf(v.z); o.w = f2bf(v.w);
  reinterpret_cast<ushort4*>(out)[i] = o;
}

// ------------- transpose fp32 [K][N] -> bf16 [N][K] -------------
__global__ __launch_bounds__(256) void k_transpose(const float* __restrict__ W,
                                                   ushort* __restrict__ Wt,
                                                   int N, int K) {
  __shared__ float tile[32][33];
  int bx = blockIdx.x * 32;  // N dim
  int by = blockIdx.y * 32;  // K dim
  int tx = threadIdx.x, ty = threadIdx.y;  // 32 x 8
#pragma unroll
  for (int i = 0; i < 32; i += 8)
    tile[ty + i][tx] = W[(size_t)(by + ty + i) * N + bx + tx];
  __syncthreads();
#pragma unroll
  for (int i = 0; i < 32; i += 8)
    Wt[(size_t)(bx + ty + i) * K + by + tx] = f2bf(tile[tx][ty + i]);
}

// ------------- GEMM: C = A[M][K] bf16 * Bt[N][K] bf16 -------------
// 128x128 tile, BK=32, 4 waves. 4-slot LDS ring, depth-3 global_load_lds
// prefetch (issue t+3, wait vmcnt(12); tail 8/4/0), raw barrier pair per
// K-step; both-sides LDS swizzle (conflict-free ds_read_b128).
// MODE 0: fp32 C stride N. MODE 1: bf16 C stride N.
// MODE 2: bf16 C, col remap n->(n/3)*4+n%3, row stride 4096 (SRU interleave).
template <int MODE>
__global__ __launch_bounds__(256) void k_gemm(const ushort* __restrict__ A,
                                              const ushort* __restrict__ Bt,
                                              void* __restrict__ Cv,
                                              int K, int N) {
  __shared__ __align__(16) ushort lsA[4][4096];
  __shared__ __align__(16) ushort lsB[4][4096];
  const int tid = threadIdx.x;
  const int bm = blockIdx.x, bn = blockIdx.y;
  const int w = tid >> 6, l = tid & 63;
  const int wm = (w >> 1) * 64, wn = (w & 1) * 64;
  const int lr = l & 15, lg = l >> 4;
  f32x4 acc[4][4] = {};
  const int srow = tid >> 2;                               // 0..63
  const int scol = (((tid & 3) ^ ((srow >> 1) & 3))) * 8;  // swizzled source chunk
  const ushort* Ag = A + (size_t)(bm * 128 + srow) * K + scol;
  const ushort* Bg = Bt + (size_t)(bn * 128 + srow) * K + scol;
  const int nt = K >> 5;
  const int rxor = (lr >> 1) & 3;                          // read-side XOR

#define GEMM_ISSUE(SL, KT)                                          \
  {                                                                 \
    GLDS(Ag + (KT), &lsA[SL][w * 512], 16);                         \
    GLDS(Ag + (size_t)64 * K + (KT), &lsA[SL][2048 + w * 512], 16); \
    GLDS(Bg + (KT), &lsB[SL][w * 512], 16);                         \
    GLDS(Bg + (size_t)64 * K + (KT), &lsB[SL][2048 + w * 512], 16); \
  }

  GEMM_ISSUE(0, 0);
  GEMM_ISSUE(1, 32);
  GEMM_ISSUE(2, 64);
  for (int t = 0; t < nt; ++t) {
    const int cur = t & 3;
    if (t + 3 < nt) {
      GEMM_ISSUE((t + 3) & 3, (t + 3) * 32);
      asm volatile("s_waitcnt vmcnt(12)" ::: "memory");  // tile t landed (own)
    } else {
      const int rem = nt - 1 - t;
      if (rem == 2)      asm volatile("s_waitcnt vmcnt(8)" ::: "memory");
      else if (rem == 1) asm volatile("s_waitcnt vmcnt(4)" ::: "memory");
      else               asm volatile("s_waitcnt vmcnt(0)" ::: "memory");
    }
    asm volatile("s_barrier" ::: "memory");  // all waves' tile-t DMA landed
    short8 af[4], bfr[4];
#pragma unroll
    for (int i = 0; i < 4; ++i)
      af[i] = *(const short8*)&lsA[cur][(wm + i * 16 + lr) * 32 + ((lg ^ rxor) * 8)];
#pragma unroll
    for (int j = 0; j < 4; ++j)
      bfr[j] = *(const short8*)&lsB[cur][(wn + j * 16 + lr) * 32 + ((lg ^ rxor) * 8)];
#pragma unroll
    for (int i = 0; i < 4; ++i)
#pragma unroll
      for (int j = 0; j < 4; ++j)
        acc[i][j] = __builtin_amdgcn_mfma_f32_16x16x32_bf16(af[i], bfr[j], acc[i][j], 0, 0, 0);
    asm volatile("s_barrier" ::: "memory");  // reads done before slot reuse
  }
#undef GEMM_ISSUE
  const int row0 = bm * 128 + wm + lg * 4;
  if (MODE == 2) {
    ushort* Cb = (ushort*)Cv;
#pragma unroll
    for (int j = 0; j < 4; ++j) {
      unsigned n = bn * 128 + wn + j * 16 + lr;
      unsigned c2 = n / 3u;
      unsigned col = c2 * 4 + (n - c2 * 3u);
#pragma unroll
      for (int i = 0; i < 4; ++i)
#pragma unroll
        for (int r = 0; r < 4; ++r)
          Cb[(size_t)(row0 + i * 16 + r) * 4096 + col] = f2bf(acc[i][j][r]);
    }
  } else if (MODE == 1) {
    ushort* Cb = (ushort*)Cv + (size_t)row0 * N + bn * 128 + wn + lr;
#pragma unroll
    for (int i = 0; i < 4; ++i)
#pragma unroll
      for (int j = 0; j < 4; ++j)
#pragma unroll
        for (int r = 0; r < 4; ++r)
          Cb[(size_t)(i * 16 + r) * N + j * 16] = f2bf(acc[i][j][r]);
  } else {
    float* Cb = (float*)Cv + (size_t)row0 * N + bn * 128 + wn + lr;
#pragma unroll
    for (int i = 0; i < 4; ++i)
#pragma unroll
      for (int j = 0; j < 4; ++j)
#pragma unroll
        for (int r = 0; r < 4; ++r)
          Cb[(size_t)(i * 16 + r) * N + j * 16] = acc[i][j][r];
  }
}

// ------------- SRU recurrence v10: interleaved U, single 8B load/step ------
// U rows [8192][4096] ushort: channel c2 (0..1023) owns [u0,u1,u2,res] at
// c2*4. res: layer0 from its KK=4 GEMM; layers1-5 written by previous sru
// (WRITE_NEXT) into slot3. 256 blocks x 64 lanes; lane owns c2 =
// dir*512+cg*64+lane. Per step: ONE uint2 load (wave: 512B contiguous).
// Ring 4 slots x 8 steps (64 VGPR payload), statically indexed.
// 512 steps = 64 tiles: ii=0..14 (tiles 0..59) + tail 60..63.
// Wait safety: steady wait has 24 loads newer than tile i's last load ->
// vmcnt(24) guarantees landed (in-order loads; stores only add). Tail 16/8/0.
template <int WRITE_NEXT>
__global__ __launch_bounds__(64, 1) void sru_rec9(const ushort* __restrict__ U,
                                                  const float* __restrict__ v,
                                                  const float* __restrict__ bb,
                                                  ushort* __restrict__ H,
                                                  ushort* __restrict__ Un) {
  const int lane = threadIdx.x;
  const int blk = blockIdx.x;                 // 0..255 : b(4) dir(1) cg(3)
  const int b = blk >> 4, rem = blk & 15, dir = rem >> 3, cg = rem & 7;
  const int c2 = dir * 512 + cg * 64 + lane;
  const float vf = v[c2], vr = v[1024 + c2];
  const float bfv = bb[c2], brv = bb[1024 + c2];
  const float vfn = -vf, vrn = -vr;
  const float kf0 = -bfv, kr0 = -brv;
  const int tstep = dir ? -1 : 1;
  const int t0 = dir ? 511 : 0;
  const ushort* Ub = U + (size_t)b * 512 * 4096 + c2 * 4;
  ushort* Hb = H + (size_t)b * 512 * 1024 + c2;
  ushort* Unb = Un + (size_t)b * 512 * 4096 + c2 * 4 + 3;

  uint2v q[4][8];

#define SR_ISSUE(J, TI)                                                        \
  {                                                                            \
    const int base_ = (TI) * 8;                                                \
    _Pragma("unroll")                                                          \
    for (int t = 0; t < 8; ++t) {                                              \
      int tt = t0 + tstep * (base_ + t);                                       \
      q[J][t] = *(const uint2v*)(Ub + (size_t)tt * 4096);                      \
    }                                                                          \
  }

#define SR_COMP(J, TI)                                                         \
  {                                                                            \
    _Pragma("unroll")                                                          \
    for (int s = 0; s < 8; ++s) {                                              \
      unsigned lo = q[J][s].x, hi = q[J][s].y;                                 \
      float u0 = __builtin_bit_cast(float, lo << 16);                          \
      float u1 = __builtin_bit_cast(float, lo & 0xffff0000u);                  \
      float u2 = __builtin_bit_cast(float, hi << 16);                          \
      float uR = __builtin_bit_cast(float, hi & 0xffff0000u);                  \
      float ef = __expf(__builtin_fmaf(vfn, c, kf0 - u1));                     \
      float f = __builtin_amdgcn_rcpf(1.f + ef);                               \
      c = __builtin_fmaf(f, c - u0, u0);                                       \
      float er = __expf(__builtin_fmaf(vrn, c, kr0 - u2));                     \
      float r = __builtin_amdgcn_rcpf(1.f + er);                               \
      float hh = __builtin_fmaf(r, c - uR, uR);                                \
      ushort hb = f2bf(hh);                                                    \
      int tt = t0 + tstep * ((TI) * 8 + s);                                    \
      Hb[(size_t)tt * 1024] = hb;                                              \
      if (WRITE_NEXT) Unb[(size_t)tt * 4096] = hb;                             \
    }                                                                          \
  }

  SR_ISSUE(0, 0)
  SR_ISSUE(1, 1)
  SR_ISSUE(2, 2)
  float c = 0.f;
#pragma unroll 1
  for (int ii = 0; ii < 15; ++ii) {   // tiles 0..59 (64 tiles = 512 steps)
#define TILE_J(J)                                                              \
    {                                                                          \
      const int i = ii * 4 + (J);                                              \
      SR_ISSUE((((J) + 3) & 3), i + 3)                                         \
      asm volatile("s_waitcnt vmcnt(24)" ::: "memory");                        \
      SR_COMP(J, i)                                                            \
    }
    TILE_J(0) TILE_J(1) TILE_J(2) TILE_J(3)
#undef TILE_J
  }
  // tail: tiles 60..63 (63 issued here; 60..62 issued in loop)
  SR_ISSUE(3, 63)
  asm volatile("s_waitcnt vmcnt(24)" ::: "memory");
  SR_COMP(0, 60)
  asm volatile("s_waitcnt vmcnt(16)" ::: "memory");
  SR_COMP(1, 61)
  asm volatile("s_waitcnt vmcnt(8)" ::: "memory");
  SR_COMP(2, 62)
  asm volatile("s_waitcnt vmcnt(0)" ::: "memory");
  SR_COMP(3, 63)
#undef SR_ISSUE
#undef SR_COMP
}

// ------------- head helpers -------------
__global__ __launch_bounds__(256) void k_buildW2(const float* __restrict__ w2l,
                                                 const float* __restrict__ w2m,
                                                 const float* __restrict__ w2k,
                                                 ushort* __restrict__ Wt2) {
  int i = blockIdx.x * 256 + threadIdx.x;  // over 128*1024
  if (i >= 128 * 1024) return;
  int n = i >> 10, k = i & 1023;
  float vv = 0.f;
  if (n < 21 && k < 512) vv = w2l[k * 21 + n];
  else if (n >= 21 && n < 23 && k >= 512) vv = w2m[(k - 512) * 2 + (n - 21)];
  else if (n >= 23 && n < 25 && k >= 512) vv = w2k[(k - 512) * 2 + (n - 23)];
  Wt2[i] = f2bf(vv);
}

__global__ __launch_bounds__(64) void k_bias25(const float* __restrict__ b1l,
                                               const float* __restrict__ b1a,
                                               const float* __restrict__ w2l,
                                               const float* __restrict__ b2l,
                                               const float* __restrict__ w2m,
                                               const float* __restrict__ b2m,
                                               const float* __restrict__ w2k,
                                               const float* __restrict__ b2k,
                                               float* __restrict__ b2adj) {
  int o = threadIdx.x;
  if (o >= 25) return;
  float s;
  if (o < 21) {
    s = b2l[o];
    for (int k = 0; k < 512; ++k) s += b1l[k] * w2l[k * 21 + o];
  } else if (o < 23) {
    s = b2m[o - 21];
    for (int k = 0; k < 512; ++k) s += b1a[k] * w2m[k * 2 + (o - 21)];
  } else {
    s = b2k[o - 23];
    for (int k = 0; k < 512; ++k) s += b1a[k] * w2k[k * 2 + (o - 23)];
  }
  b2adj[o] = s;
}

__global__ __launch_bounds__(64) void k_act(const float* __restrict__ T,
                                            const float* __restrict__ b2adj,
                                            float* __restrict__ out) {
  const int row = blockIdx.x;
  const int lane = threadIdx.x;
  float myv = 0.f;
  if (lane < 25) myv = T[(size_t)row * 128 + lane] + b2adj[lane];
  float x = (lane < 21) ? myv : -1e30f;
#pragma unroll
  for (int off = 32; off; off >>= 1) x = fmaxf(x, __shfl_xor(x, off));
  float e = (lane < 21) ? expf(myv - x) : 0.f;
#pragma unroll
  for (int off = 32; off; off >>= 1) e += __shfl_xor(e, off);
  float lse = x + logf(e);
  if (lane < 21) {
    out[(size_t)row * 21 + lane] = myv - lse;
  } else if (lane < 23) {
    out[172032 + row * 2 + (lane - 21)] = tanhf(myv) * 3.14159265358979323846f;
  } else if (lane < 25) {
    float sp = (myv > 20.f) ? myv : log1pf(expf(myv));
    out[188416 + row * 2 + (lane - 23)] = 5.f + sp;
  }
}

extern "C" void kernel_launch(void* const* d_in, const int* in_sizes, int n_in,
                              void* d_out, int out_size, void* d_ws, size_t ws_size,
                              hipStream_t stream) {
  (void)in_sizes; (void)n_in; (void)out_size; (void)ws_size;
  const float* input = (const float*)d_in[0];
  const float* sw[6]; const float* sv[6]; const float* sb[6];
  for (int l = 0; l < 6; ++l) {
    sw[l] = (const float*)d_in[2 + 3 * l];
    sv[l] = (const float*)d_in[3 + 3 * l];
    sb[l] = (const float*)d_in[4 + 3 * l];
  }
  const float* fc1lw = (const float*)d_in[20];
  const float* fc1lb = (const float*)d_in[21];
  const float* fc2lw = (const float*)d_in[22];
  const float* fc2lb = (const float*)d_in[23];
  const float* fc1aw = (const float*)d_in[24];
  const float* fc1ab = (const float*)d_in[25];
  const float* fc2mw = (const float*)d_in[26];
  const float* fc2mb = (const float*)d_in[27];
  const float* fc2kw = (const float*)d_in[28];
  const float* fc2kb = (const float*)d_in[29];

  char* ws = (char*)d_ws;
  ushort* Ua = (ushort*)ws;                                // 64 MiB [8192][4096]
  ushort* Ubf = (ushort*)(ws + 67108864);                  // 64 MiB
  ushort* Hcat2 = (ushort*)ws;                             // 16 MiB (reuses Ua after layers)
  float* T = (float*)(ws + 33554432);                      // 4 MiB (inside Ua region)
  ushort* H0 = (ushort*)(ws + 134217728);                  // 16 MiB
  ushort* H1 = (ushort*)(ws + 150994944);                  // 16 MiB
  ushort* X0 = (ushort*)(ws + 167772160);                  // 8 MiB
  const size_t wbase = 176160768;
  ushort* Wtl[6];
  Wtl[0] = (ushort*)(ws + wbase);                          // 4 MiB
  for (int l = 1; l < 6; ++l)
    Wtl[l] = (ushort*)(ws + wbase + 4194304 + (size_t)(l - 1) * 6291456);  // 6 MiB each
  ushort* Wfc = (ushort*)(ws + wbase + 4194304 + 5ull * 6291456);          // 2 MiB
  ushort* Wt2 = (ushort*)(ws + wbase + 37748736);          // 256 KiB
  float* b2adj = (float*)(ws + wbase + 38010880);          // 100 B

  // 1. input -> bf16; head weight prep
  k_cvt<<<4096, 256, 0, stream>>>(input, X0, 8192 * 512 / 4);
  k_buildW2<<<512, 256, 0, stream>>>(fc2lw, fc2mw, fc2kw, Wt2);
  k_bias25<<<1, 64, 0, stream>>>(fc1lb, fc1ab, fc2lw, fc2lb, fc2mw, fc2mb,
                                 fc2kw, fc2kb, b2adj);

  // 2. weight transposes -> bf16 [N][K] (plain; col order ch*KK+j)
  k_transpose<<<dim3(128, 16), dim3(32, 8), 0, stream>>>(sw[0], Wtl[0], 4096, 512);
  for (int l = 1; l < 6; ++l)
    k_transpose<<<dim3(96, 32), dim3(32, 8), 0, stream>>>(sw[l], Wtl[l], 3072, 1024);
  k_transpose<<<dim3(16, 32), dim3(32, 8), 0, stream>>>(fc1lw, Wfc, 512, 1024);
  k_transpose<<<dim3(16, 32), dim3(32, 8), 0, stream>>>(fc1aw, Wfc + (size_t)512 * 1024, 512, 1024);

  // 3. SRU layers. U ping-pong; sru(l) seeds slot3 of next layer's U.
  ushort* Ucur = Ua;
  ushort* Unxt = Ubf;
  for (int l = 0; l < 6; ++l) {
    const ushort* Ain = (l == 0) ? X0 : ((l & 1) ? H0 : H1);
    ushort* Hout = (l & 1) ? H1 : H0;
    if (l == 0)
      k_gemm<1><<<dim3(64, 32), 256, 0, stream>>>(Ain, Wtl[0], Ucur, 512, 4096);
    else
      k_gemm<2><<<dim3(64, 24), 256, 0, stream>>>(Ain, Wtl[l], Ucur, 1024, 3072);
    if (l < 5)
      sru_rec9<1><<<256, 64, 0, stream>>>(Ucur, sv[l], sb[l], Hout, Unxt);
    else
      sru_rec9<0><<<256, 64, 0, stream>>>(Ucur, sv[l], sb[l], Hout, Unxt);
    ushort* tmp = Ucur; Ucur = Unxt; Unxt = tmp;
  }

  // 4. head fc1 (logits|angles fused), bf16 out: [8192,1024] = H1 x Wfc
  k_gemm<1><<<dim3(64, 8), 256, 0, stream>>>(H1, Wfc, Hcat2, 1024, 1024);

  // 5. head fc2: [8192,128] = Hcat2[8192,1024] x Wt2[128,1024] (fp32 out)
  k_gemm<0><<<dim3(64, 1), 256, 0, stream>>>(Hcat2, Wt2, T, 1024, 128);

  // 6. activations -> out
  k_act<<<8192, 64, 0, stream>>>(T, b2adj, (float*)d_out);
}

// Round 15
// 762.171 us; speedup vs baseline: 1.1280x; 1.1280x over previous
//
#include <hip/hip_runtime.h>

typedef __attribute__((ext_vector_type(8))) short short8;
typedef __attribute__((ext_vector_type(4))) float f32x4;

__device__ __forceinline__ ushort f2bf(float x) {
  unsigned u = __builtin_bit_cast(unsigned, x);
  u = (u + 0x7fffu + ((u >> 16) & 1u)) >> 16;
  return (ushort)u;
}
__device__ __forceinline__ float bf2f(ushort x) {
  return __builtin_bit_cast(float, ((unsigned)x) << 16);
}

// global -> LDS direct DMA (k_gemm staging)
#define AS1CP(p) ((const __attribute__((address_space(1))) unsigned int*)(p))
#define AS3CP(p) ((__attribute__((address_space(3))) unsigned int*)(p))
#define GLDS(g, l, SZ) __builtin_amdgcn_global_load_lds(AS1CP(g), AS3CP(l), SZ, 0, 0)

// ---------------- input fp32 -> bf16 ----------------
__global__ __launch_bounds__(256) void k_cvt(const float* __restrict__ in,
                                             ushort* __restrict__ out, int n4) {
  int i = blockIdx.x * 256 + threadIdx.x;
  if (i >= n4) return;
  float4 v = reinterpret_cast<const float4*>(in)[i];
  ushort4 o;
  o.x = f2bf(v.x); o.y = f2bf(v.y); o.z = f2bf(v.z); o.w = f2bf(v.w);
  reinterpret_cast<ushort4*>(out)[i] = o;
}

// ------------- transpose fp32 [K][N] -> bf16 [N][K] (plain) -------------
__global__ __launch_bounds__(256) void k_transpose(const float* __restrict__ W,
                                                   ushort* __restrict__ Wt,
                                                   int N, int K) {
  __shared__ float tile[32][33];
  int bx = blockIdx.x * 32;  // N dim
  int by = blockIdx.y * 32;  // K dim
  int tx = threadIdx.x, ty = threadIdx.y;  // 32 x 8
#pragma unroll
  for (int i = 0; i < 32; i += 8)
    tile[ty + i][tx] = W[(size_t)(by + ty + i) * N + bx + tx];
  __syncthreads();
#pragma unroll
  for (int i = 0; i < 32; i += 8)
    Wt[(size_t)(bx + ty + i) * K + by + tx] = f2bf(tile[tx][ty + i]);
}

// ------ transpose + planar-pair permutation for SRU weights ------
// orig col c = ch*KKp + j (ch=0..1023). newcol: j<2 -> ch*2+j ; j==2 -> 2048+ch ;
// j==3 -> 3072+ch. U rows then read as [u0u1 pairs | u2 plane | res plane].
template <int KKp>
__global__ __launch_bounds__(256) void k_transpose_sru(const float* __restrict__ W,
                                                       ushort* __restrict__ Wt,
                                                       int N, int K) {
  __shared__ float tile[32][33];
  int bx = blockIdx.x * 32;  // orig col dim
  int by = blockIdx.y * 32;  // K dim
  int tx = threadIdx.x, ty = threadIdx.y;  // 32 x 8
#pragma unroll
  for (int i = 0; i < 32; i += 8)
    tile[ty + i][tx] = W[(size_t)(by + ty + i) * N + bx + tx];
  __syncthreads();
#pragma unroll
  for (int i = 0; i < 32; i += 8) {
    int c = bx + ty + i;
    int ch = c / KKp, j = c - ch * KKp;
    int nc = (j < 2) ? (ch * 2 + j) : ((j == 2) ? (2048 + ch) : (3072 + ch));
    Wt[(size_t)nc * K + by + tx] = f2bf(tile[tx][ty + i]);
  }
}

// ------------- GEMM: C[M][N] = A[M][K] bf16 * Bt[N][K] bf16 -------------
// 128x128 tile, BK=64 (two BK=32 sub-tiles), 4 waves. 2-slot LDS ring with
// global_load_lds staging (8 issues/K-step), counted vmcnt(8), raw barrier
// pair per K-step (32 MFMA per pair); both-sides LDS swizzle (conflict-free
// ds_read_b128). K must be a multiple of 64.
template <int BF16OUT>
__global__ __launch_bounds__(256) void k_gemm(const ushort* __restrict__ A,
                                              const ushort* __restrict__ Bt,
                                              void* __restrict__ Cv,
                                              int K, int N) {
  __shared__ __align__(16) ushort lsA[2][2][4096];
  __shared__ __align__(16) ushort lsB[2][2][4096];
  const int tid = threadIdx.x;
  const int bm = blockIdx.x, bn = blockIdx.y;
  const int w = tid >> 6, l = tid & 63;
  const int wm = (w >> 1) * 64, wn = (w & 1) * 64;
  const int lr = l & 15, lg = l >> 4;
  f32x4 acc[4][4] = {};
  const int srow = tid >> 2;                               // 0..63
  const int scol = (((tid & 3) ^ ((srow >> 1) & 3))) * 8;  // swizzled source chunk
  const ushort* Ag = A + (size_t)(bm * 128 + srow) * K + scol;
  const ushort* Bg = Bt + (size_t)(bn * 128 + srow) * K + scol;
  const int nt = K >> 6;
  const int rxor = (lr >> 1) & 3;                          // read-side XOR

#define GEMM_ISSUE(SL, KT)                                                  \
  {                                                                         \
    GLDS(Ag + (KT), &lsA[SL][0][w * 512], 16);                              \
    GLDS(Ag + (size_t)64 * K + (KT), &lsA[SL][0][2048 + w * 512], 16);      \
    GLDS(Bg + (KT), &lsB[SL][0][w * 512], 16);                              \
    GLDS(Bg + (size_t)64 * K + (KT), &lsB[SL][0][2048 + w * 512], 16);      \
    GLDS(Ag + (KT) + 32, &lsA[SL][1][w * 512], 16);                         \
    GLDS(Ag + (size_t)64 * K + (KT) + 32, &lsA[SL][1][2048 + w * 512], 16); \
    GLDS(Bg + (KT) + 32, &lsB[SL][1][w * 512], 16);                         \
    GLDS(Bg + (size_t)64 * K + (KT) + 32, &lsB[SL][1][2048 + w * 512], 16); \
  }

  GEMM_ISSUE(0, 0);
  for (int t = 0; t < nt; ++t) {
    const int cur = t & 1;
    if (t + 1 < nt) {
      GEMM_ISSUE(cur ^ 1, (t + 1) * 64);
      asm volatile("s_waitcnt vmcnt(8)" ::: "memory");  // own slot landed
    } else {
      asm volatile("s_waitcnt vmcnt(0)" ::: "memory");
    }
    asm volatile("s_barrier" ::: "memory");  // all waves' tile-t DMA landed
#pragma unroll
    for (int kk = 0; kk < 2; ++kk) {
      short8 af[4], bfr[4];
#pragma unroll
      for (int i = 0; i < 4; ++i)
        af[i] = *(const short8*)&lsA[cur][kk][(wm + i * 16 + lr) * 32 + ((lg ^ rxor) * 8)];
#pragma unroll
      for (int j = 0; j < 4; ++j)
        bfr[j] = *(const short8*)&lsB[cur][kk][(wn + j * 16 + lr) * 32 + ((lg ^ rxor) * 8)];
#pragma unroll
      for (int i = 0; i < 4; ++i)
#pragma unroll
        for (int j = 0; j < 4; ++j)
          acc[i][j] = __builtin_amdgcn_mfma_f32_16x16x32_bf16(af[i], bfr[j], acc[i][j], 0, 0, 0);
    }
    asm volatile("s_barrier" ::: "memory");  // reads done before slot reuse
  }
#undef GEMM_ISSUE
  const size_t cbase = (size_t)(bm * 128 + wm + lg * 4) * N + bn * 128 + wn + lr;
  if (BF16OUT) {
    ushort* Cb = (ushort*)Cv + cbase;
#pragma unroll
    for (int i = 0; i < 4; ++i)
#pragma unroll
      for (int j = 0; j < 4; ++j)
#pragma unroll
        for (int r = 0; r < 4; ++r)
          Cb[(size_t)(i * 16 + r) * N + j * 16] = f2bf(acc[i][j][r]);
  } else {
    float* Cb = (float*)Cv + cbase;
#pragma unroll
    for (int i = 0; i < 4; ++i)
#pragma unroll
      for (int j = 0; j < 4; ++j)
#pragma unroll
        for (int r = 0; r < 4; ++r)
          Cb[(size_t)(i * 16 + r) * N + j * 16] = acc[i][j][r];
  }
}

// ------------- SRU recurrence v9b: planar bf16 U, 64-lane register ring ----
// (identical to round 13's passing version)
__global__ __launch_bounds__(64, 1) void sru_rec8(const ushort* __restrict__ U, int NU,
                                                  const ushort* __restrict__ R, int RS,
                                                  const float* __restrict__ v,
                                                  const float* __restrict__ bb,
                                                  ushort* __restrict__ H) {
  const int lane = threadIdx.x;
  const int blk = blockIdx.x;                 // 0..255 : b(4) dir(1) cg(3)
  const int b = blk >> 4, rem = blk & 15, dir = rem >> 3, cg = rem & 7;
  const int ch = dir * 512 + cg * 64 + lane;
  const float vf = v[ch], vr = v[1024 + ch];
  const float bfv = bb[ch], brv = bb[1024 + ch];
  const float vfn = -vf, vrn = -vr;
  const float kf0 = -bfv, kr0 = -brv;
  const int tstep = dir ? -1 : 1;
  const int t0 = dir ? 511 : 0;
  const ushort* U01 = U + (size_t)b * 512 * NU + ch * 2;
  const ushort* U2  = U + (size_t)b * 512 * NU + 2048 + ch;
  const ushort* Rb  = R + (size_t)b * 512 * RS + ch;
  ushort* Hb = H + (size_t)b * 512 * 1024 + ch;

  unsigned q01[4][8];
  ushort q2[4][8], qr[4][8];

#define SR_ISSUE(J, TI)                                                        \
  {                                                                            \
    const int base_ = (TI) * 8;                                                \
    _Pragma("unroll")                                                          \
    for (int t = 0; t < 8; ++t) {                                              \
      int tt = t0 + tstep * (base_ + t);                                       \
      q01[J][t] = *(const unsigned*)(U01 + (size_t)tt * NU);                   \
      q2[J][t] = U2[(size_t)tt * NU];                                          \
      qr[J][t] = Rb[(size_t)tt * RS];                                          \
    }                                                                          \
  }

#define SR_COMP(J, TI)                                                         \
  {                                                                            \
    _Pragma("unroll")                                                          \
    for (int s = 0; s < 8; ++s) {                                              \
      float u0 = __builtin_bit_cast(float, q01[J][s] << 16);                   \
      float u1 = __builtin_bit_cast(float, q01[J][s] & 0xffff0000u);           \
      float u2 = bf2f(q2[J][s]);                                               \
      float uR = bf2f(qr[J][s]);                                               \
      float ef = __expf(__builtin_fmaf(vfn, c, kf0 - u1));                     \
      float f = __builtin_amdgcn_rcpf(1.f + ef);                               \
      c = __builtin_fmaf(f, c - u0, u0);                                       \
      float er = __expf(__builtin_fmaf(vrn, c, kr0 - u2));                     \
      float r = __builtin_amdgcn_rcpf(1.f + er);                               \
      float hh = __builtin_fmaf(r, c - uR, uR);                                \
      Hb[(size_t)(t0 + tstep * ((TI) * 8 + s)) * 1024] = f2bf(hh);             \
    }                                                                          \
  }

  SR_ISSUE(0, 0)
  SR_ISSUE(1, 1)
  SR_ISSUE(2, 2)
  float c = 0.f;
#pragma unroll 1
  for (int ii = 0; ii < 15; ++ii) {   // tiles 0..59 (64 tiles total = 512 steps)
#define TILE_J(J)                                                              \
    {                                                                          \
      const int i = ii * 4 + (J);                                              \
      SR_ISSUE((((J) + 3) & 3), i + 3)                                         \
      asm volatile("s_waitcnt vmcnt(63)" ::: "memory");                        \
      SR_COMP(J, i)                                                            \
    }
    TILE_J(0) TILE_J(1) TILE_J(2) TILE_J(3)
#undef TILE_J
  }
  // tail: tiles 60..63 (tile 63 issued here; 60..62 issued in loop)
  SR_ISSUE(3, 63)
  asm volatile("s_waitcnt vmcnt(63)" ::: "memory");
  SR_COMP(0, 60)
  asm volatile("s_waitcnt vmcnt(48)" ::: "memory");
  SR_COMP(1, 61)
  asm volatile("s_waitcnt vmcnt(24)" ::: "memory");
  SR_COMP(2, 62)
  asm volatile("s_waitcnt vmcnt(0)" ::: "memory");
  SR_COMP(3, 63)
#undef SR_ISSUE
#undef SR_COMP
}

// ------------- head helpers -------------
__global__ __launch_bounds__(256) void k_buildW2(const float* __restrict__ w2l,
                                                 const float* __restrict__ w2m,
                                                 const float* __restrict__ w2k,
                                                 ushort* __restrict__ Wt2) {
  int i = blockIdx.x * 256 + threadIdx.x;  // over 128*1024
  if (i >= 128 * 1024) return;
  int n = i >> 10, k = i & 1023;
  float vv = 0.f;
  if (n < 21 && k < 512) vv = w2l[k * 21 + n];
  else if (n >= 21 && n < 23 && k >= 512) vv = w2m[(k - 512) * 2 + (n - 21)];
  else if (n >= 23 && n < 25 && k >= 512) vv = w2k[(k - 512) * 2 + (n - 23)];
  Wt2[i] = f2bf(vv);
}

__global__ __launch_bounds__(64) void k_bias25(const float* __restrict__ b1l,
                                               const float* __restrict__ b1a,
                                               const float* __restrict__ w2l,
                                               const float* __restrict__ b2l,
                                               const float* __restrict__ w2m,
                                               const float* __restrict__ b2m,
                                               const float* __restrict__ w2k,
                                               const float* __restrict__ b2k,
                                               float* __restrict__ b2adj) {
  int o = threadIdx.x;
  if (o >= 25) return;
  float s;
  if (o < 21) {
    s = b2l[o];
    for (int k = 0; k < 512; ++k) s += b1l[k] * w2l[k * 21 + o];
  } else if (o < 23) {
    s = b2m[o - 21];
    for (int k = 0; k < 512; ++k) s += b1a[k] * w2m[k * 2 + (o - 21)];
  } else {
    s = b2k[o - 23];
    for (int k = 0; k < 512; ++k) s += b1a[k] * w2k[k * 2 + (o - 23)];
  }
  b2adj[o] = s;
}

__global__ __launch_bounds__(64) void k_act(const float* __restrict__ T,
                                            const float* __restrict__ b2adj,
                                            float* __restrict__ out) {
  const int row = blockIdx.x;
  const int lane = threadIdx.x;
  float myv = 0.f;
  if (lane < 25) myv = T[(size_t)row * 128 + lane] + b2adj[lane];
  float x = (lane < 21) ? myv : -1e30f;
#pragma unroll
  for (int off = 32; off; off >>= 1) x = fmaxf(x, __shfl_xor(x, off));
  float e = (lane < 21) ? expf(myv - x) : 0.f;
#pragma unroll
  for (int off = 32; off; off >>= 1) e += __shfl_xor(e, off);
  float lse = x + logf(e);
  if (lane < 21) {
    out[(size_t)row * 21 + lane] = myv - lse;
  } else if (lane < 23) {
    out[172032 + row * 2 + (lane - 21)] = tanhf(myv) * 3.14159265358979323846f;
  } else if (lane < 25) {
    float sp = (myv > 20.f) ? myv : log1pf(expf(myv));
    out[188416 + row * 2 + (lane - 23)] = 5.f + sp;
  }
}

extern "C" void kernel_launch(void* const* d_in, const int* in_sizes, int n_in,
                              void* d_out, int out_size, void* d_ws, size_t ws_size,
                              hipStream_t stream) {
  (void)in_sizes; (void)n_in; (void)out_size; (void)ws_size;
  const float* input = (const float*)d_in[0];
  const float* sw[6]; const float* sv[6]; const float* sb[6];
  for (int l = 0; l < 6; ++l) {
    sw[l] = (const float*)d_in[2 + 3 * l];
    sv[l] = (const float*)d_in[3 + 3 * l];
    sb[l] = (const float*)d_in[4 + 3 * l];
  }
  const float* fc1lw = (const float*)d_in[20];
  const float* fc1lb = (const float*)d_in[21];
  const float* fc2lw = (const float*)d_in[22];
  const float* fc2lb = (const float*)d_in[23];
  const float* fc1aw = (const float*)d_in[24];
  const float* fc1ab = (const float*)d_in[25];
  const float* fc2mw = (const float*)d_in[26];
  const float* fc2mb = (const float*)d_in[27];
  const float* fc2kw = (const float*)d_in[28];
  const float* fc2kb = (const float*)d_in[29];

  char* ws = (char*)d_ws;
  ushort* U = (ushort*)ws;                                 // 64 MiB (bf16 planar)
  ushort* Hcat2 = (ushort*)ws;                             // 16 MiB (reuses U after layers)
  float* T = (float*)(ws + 67108864);                      // 4 MiB
  ushort* H0 = (ushort*)(ws + 134217728);                  // 16 MiB
  ushort* H1 = (ushort*)(ws + 150994944);                  // 16 MiB
  ushort* X0 = (ushort*)(ws + 167772160);                  // 8 MiB
  const size_t wbase = 176160768;
  ushort* Wtl[6];
  Wtl[0] = (ushort*)(ws + wbase);                          // 4 MiB
  for (int l = 1; l < 6; ++l)
    Wtl[l] = (ushort*)(ws + wbase + 4194304 + (size_t)(l - 1) * 6291456);  // 6 MiB each
  ushort* Wfc = (ushort*)(ws + wbase + 4194304 + 5ull * 6291456);          // 2 MiB
  ushort* Wt2 = (ushort*)(ws + wbase + 37748736);          // 256 KiB
  float* b2adj = (float*)(ws + wbase + 38010880);          // 100 B

  // 1. input -> bf16; head weight prep
  k_cvt<<<4096, 256, 0, stream>>>(input, X0, 8192 * 512 / 4);
  k_buildW2<<<512, 256, 0, stream>>>(fc2lw, fc2mw, fc2kw, Wt2);
  k_bias25<<<1, 64, 0, stream>>>(fc1lb, fc1ab, fc2lw, fc2lb, fc2mw, fc2mb,
                                 fc2kw, fc2kb, b2adj);

  // 2. weight transposes -> bf16 [N][K], SRU ones with planar-pair permutation
  k_transpose_sru<4><<<dim3(128, 16), dim3(32, 8), 0, stream>>>(sw[0], Wtl[0], 4096, 512);
  for (int l = 1; l < 6; ++l)
    k_transpose_sru<3><<<dim3(96, 32), dim3(32, 8), 0, stream>>>(sw[l], Wtl[l], 3072, 1024);
  k_transpose<<<dim3(16, 32), dim3(32, 8), 0, stream>>>(fc1lw, Wfc, 512, 1024);
  k_transpose<<<dim3(16, 32), dim3(32, 8), 0, stream>>>(fc1aw, Wfc + (size_t)512 * 1024, 512, 1024);

  // 3. SRU layers (U is bf16 planar; res from U plane for l=0, else H_in)
  for (int l = 0; l < 6; ++l) {
    const ushort* Ain = (l == 0) ? X0 : ((l & 1) ? H0 : H1);
    ushort* Hout = (l & 1) ? H1 : H0;
    int K = (l == 0) ? 512 : 1024;
    int N = (l == 0) ? 4096 : 3072;
    k_gemm<1><<<dim3(64, N / 128), 256, 0, stream>>>(Ain, Wtl[l], U, K, N);
    if (l == 0)
      sru_rec8<<<256, 64, 0, stream>>>(U, 4096, U + 3072, 4096, sv[l], sb[l], Hout);
    else
      sru_rec8<<<256, 64, 0, stream>>>(U, 3072, Ain, 1024, sv[l], sb[l], Hout);
  }

  // 4. head fc1 (logits|angles fused), bf16 out: [8192,1024] = H1 x Wfc
  k_gemm<1><<<dim3(64, 8), 256, 0, stream>>>(H1, Wfc, Hcat2, 1024, 1024);

  // 5. head fc2: [8192,128] = Hcat2[8192,1024] x Wt2[128,1024] (fp32 out)
  k_gemm<0><<<dim3(64, 1), 256, 0, stream>>>(Hcat2, Wt2, T, 1024, 128);

  // 6. activations -> out
  k_act<<<8192, 64, 0, stream>>>(T, b2adj, (float*)d_out);
}